// Round 5
// baseline (745.806 us; speedup 1.0000x reference)
//
#include <hip/hip_runtime.h>
#include <cmath>

// Forbid FMA contraction: the reference check is a float32 numpy replay with
// individually-rounded ops. We opt into FMA explicitly (fmaf) only where
// BLAS sgemm itself uses an FMA chain.
#pragma clang fp contract(off)

#define NLV 16
#define TSZ (1u << 19)
#define TMASK (TSZ - 1u)
#define PR1 2654435761u
#define PR2 805459861u

struct ResT { float r[NLV]; };

// One hash-grid level: gathers 8 corners ONCE, accumulates forward z1 and
// returns the 6 gradient partials (d feats / d pn[axis]) in named scalars.
// All out-params are distinct named registers at each call site -> no arrays,
// no scratch.
__device__ __forceinline__ void level_fwd(
    float res, const float2* __restrict__ tl,
    const float* __restrict__ w1a, const float* __restrict__ w1b,
    float pnx, float pny, float pnz, float* z1,
    float& oxa, float& oxb, float& oya, float& oyb, float& oza, float& ozb)
{
    float fx = pnx * res, fy = pny * res, fz = pnz * res;
    float x0 = floorf(fx), y0 = floorf(fy), z0 = floorf(fz);
    float wx = fx - x0, wy = fy - y0, wz = fz - z0;
    float omx = 1.f - wx, omy = 1.f - wy, omz = 1.f - wz;
    unsigned ux = (unsigned)x0, uy = (unsigned)y0, uz = (unsigned)z0;
    unsigned hx0 = ux,        hx1 = ux + 1u;
    unsigned hy0 = uy * PR1,  hy1 = (uy + 1u) * PR1;
    unsigned hz0 = uz * PR2,  hz1 = (uz + 1u) * PR2;
    float f0 = 0.f, f1 = 0.f;
    float lxa = 0.f, lxb = 0.f, lya = 0.f, lyb = 0.f, lza = 0.f, lzb = 0.f;
#pragma unroll
    for (int c = 0; c < 8; ++c) {
        unsigned hh = ((c & 4) ? hx1 : hx0) ^ ((c & 2) ? hy1 : hy0) ^ ((c & 1) ? hz1 : hz0);
        float2 fv = tl[hh & TMASK];
        float wxv = (c & 4) ? wx : omx;
        float wyv = (c & 2) ? wy : omy;
        float wzv = (c & 1) ? wz : omz;
        // forward: wc = (x*y)*z, each op rounded; f += fv*wc sequential c=0..7
        float wgt = wxv * wyv;
        wgt = wgt * wzv;
        float t0 = fv.x * wgt;
        float t1 = fv.y * wgt;
        f0 = f0 + t0;
        f1 = f1 + t1;
        // gradient partials (sign flip by corner bit is exact)
        float pyz = wyv * wzv;
        float pxz = wxv * wzv;
        float pxy = wxv * wyv;
        float spx = (c & 4) ? pyz : -pyz;
        float spy = (c & 2) ? pxz : -pxz;
        float spz = (c & 1) ? pxy : -pxy;
        lxa = lxa + fv.x * spx;  lxb = lxb + fv.y * spx;
        lya = lya + fv.x * spy;  lyb = lyb + fv.y * spy;
        lza = lza + fv.x * spz;  lzb = lzb + fv.y * spz;
    }
    oxa = lxa; oxb = lxb; oya = lya; oyb = lyb; oza = lza; ozb = lzb;
#pragma unroll
    for (int i = 0; i < 32; ++i) {
        float acc = fmaf(f0, w1a[i], z1[i]);   // k=2l first (ascending k)
        z1[i] = fmaf(f1, w1b[i], acc);         // then k=2l+1
    }
}

__device__ __forceinline__ void level_bwd(
    float res, const float* __restrict__ w1a, const float* __restrict__ w1b,
    const float* dzv,
    float xa, float xb, float ya, float yb, float za, float zb,
    float& gx, float& gy, float& gz)
{
    float da = 0.f, db = 0.f;
#pragma unroll
    for (int i = 0; i < 32; ++i) {
        da = fmaf(w1a[i], dzv[i], da);
        db = fmaf(w1b[i], dzv[i], db);
    }
    gx = fmaf(res, fmaf(da, xa, db * xb), gx);
    gy = fmaf(res, fmaf(da, ya, db * yb), gy);
    gz = fmaf(res, fmaf(da, za, db * zb), gz);
}

// 256-VGPR budget (2 waves/SIMD, 8 waves/CU): enough for z1[32] + 96 named
// gradient partials + working set with NO scratch spill. (256,3)'s 170 cap
// forced spills in round 4 -> 497 MB scratch writes, regression.
__global__ __launch_bounds__(256, 2) void ngp_fused(
    const float* __restrict__ g_pos,
    const float* __restrict__ g_rx,
    const float* __restrict__ g_tab,
    const float* __restrict__ g_W1,
    const float* __restrict__ g_W2,
    const float* __restrict__ g_aabb,
    const int*   __restrict__ g_deg,
    float* __restrict__ g_out,
    int N, ResT rt)
{
    int n = blockIdx.x * 256 + threadIdx.x;
    if (n >= N) return;

    // ---- AABB normalize, pure fp32 single ops (bit-exact vs np fp32) ----
    float a0 = g_aabb[0], a1 = g_aabb[1], a2 = g_aabb[2];
    float s0 = fmaxf(g_aabb[3] - a0, 1e-6f);
    float s1 = fmaxf(g_aabb[4] - a1, 1e-6f);
    float s2 = fmaxf(g_aabb[5] - a2, 1e-6f);
    float posx = g_pos[3*n+0], posy = g_pos[3*n+1], posz = g_pos[3*n+2];
    float nx = (posx - a0) / s0;
    float ny = (posy - a1) / s1;
    float nz = (posz - a2) / s2;
    bool sel = (nx >= 0.f) && (nx <= 1.f) && (ny >= 0.f) && (ny <= 1.f)
            && (nz >= 0.f) && (nz <= 1.f);
    float pnx = fminf(fmaxf(nx, 0.f), 1.f);
    float pny = fminf(fmaxf(ny, 0.f), 1.f);
    float pnz = fminf(fmaxf(nz, 0.f), 1.f);

    float z1[32];
#pragma unroll
    for (int i = 0; i < 32; ++i) z1[i] = 0.f;

    const float2* tab = (const float2*)g_tab;

    // 96 named gradient partials — guaranteed registers.
    float xa0,xb0,ya0,yb0,za0,zb0,  xa1,xb1,ya1,yb1,za1,zb1;
    float xa2,xb2,ya2,yb2,za2,zb2,  xa3,xb3,ya3,yb3,za3,zb3;
    float xa4,xb4,ya4,yb4,za4,zb4,  xa5,xb5,ya5,yb5,za5,zb5;
    float xa6,xb6,ya6,yb6,za6,zb6,  xa7,xb7,ya7,yb7,za7,zb7;
    float xa8,xb8,ya8,yb8,za8,zb8,  xa9,xb9,ya9,yb9,za9,zb9;
    float xa10,xb10,ya10,yb10,za10,zb10,  xa11,xb11,ya11,yb11,za11,zb11;
    float xa12,xb12,ya12,yb12,za12,zb12,  xa13,xb13,ya13,yb13,za13,zb13;
    float xa14,xb14,ya14,yb14,za14,zb14,  xa15,xb15,ya15,yb15,za15,zb15;

#define FWD(l) level_fwd(rt.r[l], tab + (size_t)(l) * TSZ, \
                         g_W1 + (2*(l))*32, g_W1 + (2*(l)+1)*32, \
                         pnx, pny, pnz, z1, \
                         xa##l, xb##l, ya##l, yb##l, za##l, zb##l)
    FWD(0);  FWD(1);  FWD(2);  FWD(3);
    FWD(4);  FWD(5);  FWD(6);  FWD(7);
    FWD(8);  FWD(9);  FWD(10); FWD(11);
    FWD(12); FWD(13); FWD(14); FWD(15);
#undef FWD

    // ---- relu + second layer (sgemm FMA chain, ascending j) ----
    unsigned mask = 0u;
    float sh[32];
#pragma unroll
    for (int o = 0; o < 32; ++o) sh[o] = 0.f;
#pragma unroll
    for (int i = 0; i < 32; ++i) {
        bool on = (z1[i] > 0.f);
        if (on) mask |= (1u << i);
        float h = on ? z1[i] : 0.f;
        const float* w2r = g_W2 + i * 32;
#pragma unroll
        for (int o = 0; o < 32; ++o) sh[o] = fmaf(h, w2r[o], sh[o]);
    }

    const float C0c = 0.28209479177387814f;
    float d0 = C0c * sh[0], d1 = C0c * sh[1];

    // ---- view dirs + SH basis + scat ----
    float rx0 = g_rx[0], rx1 = g_rx[1], rx2 = g_rx[2];
    float dxw = rx0 - posx, dyw = rx1 - posy, dzw = rx2 - posz;
    float dnorm = sqrtf(dxw*dxw + dyw*dyw + dzw*dzw);
    float dinv = 1.f / fmaxf(dnorm, 1e-20f);
    float X = dxw * dinv, Yd = dyw * dinv, Z = dzw * dinv;
    float xx = X*X, yy = Yd*Yd, zz = Z*Z;
    float xy = X*Yd, yz = Yd*Z, xz = X*Z;
    float Yb[16];
    Yb[0]  = 0.28209479177387814f;
    Yb[1]  = -0.4886025119029199f * Yd;
    Yb[2]  =  0.4886025119029199f * Z;
    Yb[3]  = -0.4886025119029199f * X;
    Yb[4]  =  1.0925484305920792f * xy;
    Yb[5]  = -1.0925484305920792f * yz;
    Yb[6]  =  0.31539156525252005f * (2.f*zz - xx - yy);
    Yb[7]  = -1.0925484305920792f * xz;
    Yb[8]  =  0.5462742152960396f * (xx - yy);
    Yb[9]  = -0.5900435899266435f * Yd * (3.f*xx - yy);
    Yb[10] =  2.890611442640554f  * xy * Z;
    Yb[11] = -0.4570457994644658f * Yd * (4.f*zz - xx - yy);
    Yb[12] =  0.3731763325901154f * Z * (2.f*zz - 3.f*xx - 3.f*yy);
    Yb[13] = -0.4570457994644658f * X * (4.f*zz - xx - yy);
    Yb[14] =  1.445305721320277f  * Z * (xx - yy);
    Yb[15] = -0.5900435899266435f * X * (xx - 3.f*yy);

    int deg = g_deg[0];
    int nact = (deg + 1) * (deg + 1);
    float sc0 = 0.f, sc1 = 0.f;
#pragma unroll
    for (int c = 0; c < 16; ++c) {
        float yc = (c < nact) ? Yb[c] : 0.f;
        sc0 = fmaf(yc, sh[2*c+0], sc0);
        sc1 = fmaf(yc, sh[2*c+1], sc1);
    }

    float* op = g_out + (size_t)n * 39;
    op[0] = sel ? d0  : 0.f;
    op[1] = sel ? d1  : 0.f;
    op[2] = sel ? sc0 : 0.f;
    op[3] = sel ? sc1 : 0.f;
#pragma unroll
    for (int c = 0; c < 32; ++c) op[7 + c] = sel ? sh[c] : 0.f;

    // ---- backward head: q = C0*d/|d| ----
    float ss = d0*d0 + d1*d1;
    float q0 = 0.f, q1 = 0.f;
    if (ss > 0.f) {
        float sr = sqrtf(ss);
        q0 = C0c * d0 / sr;
        q1 = C0c * d1 / sr;
    }
    float dzv[32];
#pragma unroll
    for (int i = 0; i < 32; ++i) {
        float dh = fmaf(q0, g_W2[i*32+0], q1 * g_W2[i*32+1]);
        dzv[i] = ((mask >> i) & 1u) ? dh : 0.f;
    }

    // ---- gradient reduction: no gathers, pure register math ----
    float gx = 0.f, gy = 0.f, gz = 0.f;
#define BWD(l) level_bwd(rt.r[l], g_W1 + (2*(l))*32, g_W1 + (2*(l)+1)*32, dzv, \
                         xa##l, xb##l, ya##l, yb##l, za##l, zb##l, gx, gy, gz)
    BWD(0);  BWD(1);  BWD(2);  BWD(3);
    BWD(4);  BWD(5);  BWD(6);  BWD(7);
    BWD(8);  BWD(9);  BWD(10); BWD(11);
    BWD(12); BWD(13); BWD(14); BWD(15);
#undef BWD

    // ---- world-space normal ----
    float gwx = gx / s0, gwy = gy / s1, gwz = gz / s2;
    float gn = sqrtf(gwx*gwx + gwy*gwy + gwz*gwz);
    float ginv = -1.f / fmaxf(gn, 1e-20f);
    op[4] = sel ? gwx * ginv : 0.f;
    op[5] = sel ? gwy * ginv : 0.f;
    op[6] = sel ? gwz * ginv : 0.f;
}

extern "C" void kernel_launch(void* const* d_in, const int* in_sizes, int n_in,
                              void* d_out, int out_size, void* d_ws, size_t ws_size,
                              hipStream_t stream)
{
    const float* g_pos  = (const float*)d_in[0];
    const float* g_rx   = (const float*)d_in[1];
    const float* g_tab  = (const float*)d_in[2];
    const float* g_W1   = (const float*)d_in[3];
    const float* g_W2   = (const float*)d_in[4];
    const float* g_aabb = (const float*)d_in[5];
    const int*   g_deg  = (const int*)d_in[6];
    float* g_out = (float*)d_out;

    int N = in_sizes[0] / 3;

    // RES exactly as the reference: python float64 exp/log/pow, cast to fp32.
    ResT rt;
    double scale = exp((log(4096.0) - log(16.0)) / 15.0);
    for (int l = 0; l < NLV; ++l) rt.r[l] = (float)(16.0 * pow(scale, (double)l));

    int blocks = (N + 255) / 256;
    ngp_fused<<<blocks, 256, 0, stream>>>(g_pos, g_rx, g_tab, g_W1, g_W2,
                                          g_aabb, g_deg, g_out, N, rt);
}

// Round 6
// 578.699 us; speedup vs baseline: 1.2888x; 1.2888x over previous
//
#include <hip/hip_runtime.h>
#include <cmath>

// Forbid FMA contraction: the reference check is a float32 numpy replay with
// individually-rounded ops. We opt into FMA explicitly (fmaf) only where
// BLAS sgemm itself uses an FMA chain.
#pragma clang fp contract(off)

#define NLV 16
#define TSZ (1u << 19)
#define TMASK (TSZ - 1u)
#define PR1 2654435761u
#define PR2 805459861u

struct ResT { float r[NLV]; };

// Two lanes per point: lane parity p owns 8 levels (p*8..p*8+7).
// Single gather pass; forward f-values exchanged bit-exactly via shfl so both
// lanes replay the reference z1 chain in exact level order. 48 gradient
// partials per lane fit the allocator's 128-VGPR comfort zone (rounds 4/5
// proved 96/lane always spills -> 500-670 MB scratch traffic).
__global__ __launch_bounds__(256, 2) void ngp_fused(
    const float* __restrict__ g_pos,
    const float* __restrict__ g_rx,
    const float* __restrict__ g_tab,
    const float* __restrict__ g_W1,
    const float* __restrict__ g_W2,
    const float* __restrict__ g_aabb,
    const int*   __restrict__ g_deg,
    float* __restrict__ g_out,
    int N, ResT rt)
{
    int tid = blockIdx.x * 256 + threadIdx.x;
    int n = tid >> 1;
    int p = tid & 1;
    if (n >= N) return;

    // ---- AABB normalize, pure fp32 single ops (bit-exact vs np fp32) ----
    float a0 = g_aabb[0], a1 = g_aabb[1], a2 = g_aabb[2];
    float s0 = fmaxf(g_aabb[3] - a0, 1e-6f);
    float s1 = fmaxf(g_aabb[4] - a1, 1e-6f);
    float s2 = fmaxf(g_aabb[5] - a2, 1e-6f);
    float posx = g_pos[3*n+0], posy = g_pos[3*n+1], posz = g_pos[3*n+2];
    float nx = (posx - a0) / s0;
    float ny = (posy - a1) / s1;
    float nz = (posz - a2) / s2;
    bool sel = (nx >= 0.f) && (nx <= 1.f) && (ny >= 0.f) && (ny <= 1.f)
            && (nz >= 0.f) && (nz <= 1.f);
    float pnx = fminf(fmaxf(nx, 0.f), 1.f);
    float pny = fminf(fmaxf(ny, 0.f), 1.f);
    float pnz = fminf(fmaxf(nz, 0.f), 1.f);

    const float2* tab = (const float2*)g_tab;

    // ---- single gather pass over OWN 8 levels ----
    float f0o[8], f1o[8];
    float mxa[8], mxb[8], mya[8], myb[8], mza[8], mzb[8];
#pragma unroll
    for (int j = 0; j < 8; ++j) {
        float res = p ? rt.r[8+j] : rt.r[j];          // constant-index select
        const float2* tl = tab + (size_t)(p * 8 + j) * TSZ;
        float fx = pnx * res, fy = pny * res, fz = pnz * res;
        float x0 = floorf(fx), y0 = floorf(fy), z0 = floorf(fz);
        float wx = fx - x0, wy = fy - y0, wz = fz - z0;
        float omx = 1.f - wx, omy = 1.f - wy, omz = 1.f - wz;
        unsigned ux = (unsigned)x0, uy = (unsigned)y0, uz = (unsigned)z0;
        unsigned hx0 = ux,        hx1 = ux + 1u;
        unsigned hy0 = uy * PR1,  hy1 = (uy + 1u) * PR1;
        unsigned hz0 = uz * PR2,  hz1 = (uz + 1u) * PR2;
        float f0 = 0.f, f1 = 0.f;
        float lxa = 0.f, lxb = 0.f, lya = 0.f, lyb = 0.f, lza = 0.f, lzb = 0.f;
#pragma unroll
        for (int c = 0; c < 8; ++c) {
            unsigned hh = ((c & 4) ? hx1 : hx0) ^ ((c & 2) ? hy1 : hy0) ^ ((c & 1) ? hz1 : hz0);
            float2 fv = tl[hh & TMASK];
            float wxv = (c & 4) ? wx : omx;
            float wyv = (c & 2) ? wy : omy;
            float wzv = (c & 1) ? wz : omz;
            // forward: wc = (x*y)*z, each op rounded; f += fv*wc seq c=0..7
            float wgt = wxv * wyv;
            wgt = wgt * wzv;
            float t0 = fv.x * wgt;
            float t1 = fv.y * wgt;
            f0 = f0 + t0;
            f1 = f1 + t1;
            // gradient partials (sign flip by corner bit is exact)
            float pyz = wyv * wzv;
            float pxz = wxv * wzv;
            float pxy = wxv * wyv;
            float spx = (c & 4) ? pyz : -pyz;
            float spy = (c & 2) ? pxz : -pxz;
            float spz = (c & 1) ? pxy : -pxy;
            lxa = lxa + fv.x * spx;  lxb = lxb + fv.y * spx;
            lya = lya + fv.x * spy;  lyb = lyb + fv.y * spy;
            lza = lza + fv.x * spz;  lzb = lzb + fv.y * spz;
        }
        f0o[j] = f0; f1o[j] = f1;
        mxa[j] = lxa; mxb[j] = lxb;
        mya[j] = lya; myb[j] = lyb;
        mza[j] = lza; mzb[j] = lzb;
    }

    // ---- exchange f with partner lane; build z1 in EXACT level order ----
    float z1[32];
#pragma unroll
    for (int i = 0; i < 32; ++i) z1[i] = 0.f;

    float hi0[8], hi1[8];
#pragma unroll
    for (int j = 0; j < 8; ++j) {
        float t0 = __shfl_xor(f0o[j], 1, 64);
        float t1 = __shfl_xor(f1o[j], 1, 64);
        float lo0 = p ? t0 : f0o[j];      // level j feats (bit-exact copy)
        float lo1 = p ? t1 : f1o[j];
        hi0[j] = p ? f0o[j] : t0;         // level 8+j feats
        hi1[j] = p ? f1o[j] : t1;
        const float* w1a = g_W1 + (2*j) * 32;
        const float* w1b = g_W1 + (2*j+1) * 32;
#pragma unroll
        for (int i = 0; i < 32; ++i) {
            float acc = fmaf(lo0, w1a[i], z1[i]);    // k=2j then k=2j+1
            z1[i] = fmaf(lo1, w1b[i], acc);
        }
    }
#pragma unroll
    for (int j = 0; j < 8; ++j) {
        const float* w1a = g_W1 + (2*(8+j)) * 32;
        const float* w1b = g_W1 + (2*(8+j)+1) * 32;
#pragma unroll
        for (int i = 0; i < 32; ++i) {
            float acc = fmaf(hi0[j], w1a[i], z1[i]);
            z1[i] = fmaf(hi1[j], w1b[i], acc);
        }
    }

    // ---- relu + second layer (sgemm FMA chain, ascending j) ----
    unsigned mask = 0u;
    float sh[32];
#pragma unroll
    for (int o = 0; o < 32; ++o) sh[o] = 0.f;
#pragma unroll
    for (int i = 0; i < 32; ++i) {
        bool on = (z1[i] > 0.f);
        if (on) mask |= (1u << i);
        float h = on ? z1[i] : 0.f;
        const float* w2r = g_W2 + i * 32;
#pragma unroll
        for (int o = 0; o < 32; ++o) sh[o] = fmaf(h, w2r[o], sh[o]);
    }

    const float C0c = 0.28209479177387814f;
    float d0 = C0c * sh[0], d1 = C0c * sh[1];

    // ---- view dirs + SH basis + scat ----
    float rx0 = g_rx[0], rx1 = g_rx[1], rx2 = g_rx[2];
    float dxw = rx0 - posx, dyw = rx1 - posy, dzw = rx2 - posz;
    float dnorm = sqrtf(dxw*dxw + dyw*dyw + dzw*dzw);
    float dinv = 1.f / fmaxf(dnorm, 1e-20f);
    float X = dxw * dinv, Yd = dyw * dinv, Z = dzw * dinv;
    float xx = X*X, yy = Yd*Yd, zz = Z*Z;
    float xy = X*Yd, yz = Yd*Z, xz = X*Z;
    float Yb[16];
    Yb[0]  = 0.28209479177387814f;
    Yb[1]  = -0.4886025119029199f * Yd;
    Yb[2]  =  0.4886025119029199f * Z;
    Yb[3]  = -0.4886025119029199f * X;
    Yb[4]  =  1.0925484305920792f * xy;
    Yb[5]  = -1.0925484305920792f * yz;
    Yb[6]  =  0.31539156525252005f * (2.f*zz - xx - yy);
    Yb[7]  = -1.0925484305920792f * xz;
    Yb[8]  =  0.5462742152960396f * (xx - yy);
    Yb[9]  = -0.5900435899266435f * Yd * (3.f*xx - yy);
    Yb[10] =  2.890611442640554f  * xy * Z;
    Yb[11] = -0.4570457994644658f * Yd * (4.f*zz - xx - yy);
    Yb[12] =  0.3731763325901154f * Z * (2.f*zz - 3.f*xx - 3.f*yy);
    Yb[13] = -0.4570457994644658f * X * (4.f*zz - xx - yy);
    Yb[14] =  1.445305721320277f  * Z * (xx - yy);
    Yb[15] = -0.5900435899266435f * X * (xx - 3.f*yy);

    int deg = g_deg[0];
    int nact = (deg + 1) * (deg + 1);
    float sc0 = 0.f, sc1 = 0.f;
#pragma unroll
    for (int c = 0; c < 16; ++c) {
        float yc = (c < nact) ? Yb[c] : 0.f;
        sc0 = fmaf(yc, sh[2*c+0], sc0);
        sc1 = fmaf(yc, sh[2*c+1], sc1);
    }

    // ---- split the 39 stores between the lane pair ----
    float* op = g_out + (size_t)n * 39;
    if (p == 0) {
        op[0] = sel ? d0  : 0.f;
        op[1] = sel ? d1  : 0.f;
        op[2] = sel ? sc0 : 0.f;
        op[3] = sel ? sc1 : 0.f;
#pragma unroll
        for (int c = 0; c < 13; ++c) op[7 + c] = sel ? sh[c] : 0.f;
    } else {
#pragma unroll
        for (int c = 13; c < 32; ++c) op[7 + c] = sel ? sh[c] : 0.f;
    }

    // ---- backward head: q = C0*d/|d| ----
    float ss = d0*d0 + d1*d1;
    float q0 = 0.f, q1 = 0.f;
    if (ss > 0.f) {
        float sr = sqrtf(ss);
        q0 = C0c * d0 / sr;
        q1 = C0c * d1 / sr;
    }
    float dzv[32];
#pragma unroll
    for (int i = 0; i < 32; ++i) {
        float dh = fmaf(q0, g_W2[i*32+0], q1 * g_W2[i*32+1]);
        dzv[i] = ((mask >> i) & 1u) ? dh : 0.f;
    }

    // ---- backward over OWN levels: da/db via L1-hit float4 W1 loads ----
    float gx = 0.f, gy = 0.f, gz = 0.f;
    const float4* w1v = (const float4*)g_W1;   // row r = w1v[r*8 .. r*8+7]
    int rbase = p * 16;
#pragma unroll
    for (int j = 0; j < 8; ++j) {
        const float4* wa = w1v + (size_t)(rbase + 2*j) * 8;
        const float4* wb = wa + 8;
        float da = 0.f, db = 0.f;
#pragma unroll
        for (int k = 0; k < 8; ++k) {
            float4 va = wa[k], vb = wb[k];
            da = fmaf(va.x, dzv[4*k+0], da);
            da = fmaf(va.y, dzv[4*k+1], da);
            da = fmaf(va.z, dzv[4*k+2], da);
            da = fmaf(va.w, dzv[4*k+3], da);
            db = fmaf(vb.x, dzv[4*k+0], db);
            db = fmaf(vb.y, dzv[4*k+1], db);
            db = fmaf(vb.z, dzv[4*k+2], db);
            db = fmaf(vb.w, dzv[4*k+3], db);
        }
        float res = p ? rt.r[8+j] : rt.r[j];
        gx = fmaf(res, fmaf(da, mxa[j], db * mxb[j]), gx);
        gy = fmaf(res, fmaf(da, mya[j], db * myb[j]), gy);
        gz = fmaf(res, fmaf(da, mza[j], db * mzb[j]), gz);
    }
    // combine partner halves (commutative add -> identical in both lanes)
    float tx = __shfl_xor(gx, 1, 64);
    float ty = __shfl_xor(gy, 1, 64);
    float tz = __shfl_xor(gz, 1, 64);
    gx = gx + tx; gy = gy + ty; gz = gz + tz;

    // ---- world-space normal ----
    float gwx = gx / s0, gwy = gy / s1, gwz = gz / s2;
    float gn = sqrtf(gwx*gwx + gwy*gwy + gwz*gwz);
    float ginv = -1.f / fmaxf(gn, 1e-20f);
    if (p == 0) {
        op[4] = sel ? gwx * ginv : 0.f;
        op[5] = sel ? gwy * ginv : 0.f;
        op[6] = sel ? gwz * ginv : 0.f;
    }
}

extern "C" void kernel_launch(void* const* d_in, const int* in_sizes, int n_in,
                              void* d_out, int out_size, void* d_ws, size_t ws_size,
                              hipStream_t stream)
{
    const float* g_pos  = (const float*)d_in[0];
    const float* g_rx   = (const float*)d_in[1];
    const float* g_tab  = (const float*)d_in[2];
    const float* g_W1   = (const float*)d_in[3];
    const float* g_W2   = (const float*)d_in[4];
    const float* g_aabb = (const float*)d_in[5];
    const int*   g_deg  = (const int*)d_in[6];
    float* g_out = (float*)d_out;

    int N = in_sizes[0] / 3;

    // RES exactly as the reference: python float64 exp/log/pow, cast to fp32.
    ResT rt;
    double scale = exp((log(4096.0) - log(16.0)) / 15.0);
    for (int l = 0; l < NLV; ++l) rt.r[l] = (float)(16.0 * pow(scale, (double)l));

    long long threads = 2LL * N;
    int blocks = (int)((threads + 255) / 256);
    ngp_fused<<<blocks, 256, 0, stream>>>(g_pos, g_rx, g_tab, g_W1, g_W2,
                                          g_aabb, g_deg, g_out, N, rt);
}

// Round 7
// 406.372 us; speedup vs baseline: 1.8353x; 1.4241x over previous
//
#include <hip/hip_runtime.h>
#include <cmath>

// Forbid FMA contraction: the reference check is a float32 numpy replay with
// individually-rounded ops. We opt into FMA explicitly (fmaf) only where
// BLAS sgemm itself uses an FMA chain.
#pragma clang fp contract(off)

#define NLV 16
#define TSZ (1u << 19)
#define TMASK (TSZ - 1u)
#define PR1 2654435761u
#define PR2 805459861u

struct ResT { float r[NLV]; };

// Two lanes per point: lane parity p owns 8 levels. Single gather pass.
// The 48 per-lane gradient partials live in LDS (m[row][tid] layout:
// consecutive tids -> consecutive banks -> conflict-free). Rounds 4-6 proved
// the allocator spills any >~40-float register array across the z1/sh FMA
// region (scratch = HBM traffic, 0.5 GB+); LDS replaces that at ~3 us.
__global__ __launch_bounds__(256, 2) void ngp_fused(
    const float* __restrict__ g_pos,
    const float* __restrict__ g_rx,
    const float* __restrict__ g_tab,
    const float* __restrict__ g_W1,
    const float* __restrict__ g_W2,
    const float* __restrict__ g_aabb,
    const int*   __restrict__ g_deg,
    float* __restrict__ g_out,
    int N, ResT rt)
{
    __shared__ float sm[48][256];   // 48 KiB/block

    int tid = blockIdx.x * 256 + threadIdx.x;
    int lt  = threadIdx.x;
    int n = tid >> 1;
    int p = tid & 1;
    if (n >= N) return;

    // ---- AABB normalize, pure fp32 single ops (bit-exact vs np fp32) ----
    float a0 = g_aabb[0], a1 = g_aabb[1], a2 = g_aabb[2];
    float s0 = fmaxf(g_aabb[3] - a0, 1e-6f);
    float s1 = fmaxf(g_aabb[4] - a1, 1e-6f);
    float s2 = fmaxf(g_aabb[5] - a2, 1e-6f);
    float posx = g_pos[3*n+0], posy = g_pos[3*n+1], posz = g_pos[3*n+2];
    float nx = (posx - a0) / s0;
    float ny = (posy - a1) / s1;
    float nz = (posz - a2) / s2;
    bool sel = (nx >= 0.f) && (nx <= 1.f) && (ny >= 0.f) && (ny <= 1.f)
            && (nz >= 0.f) && (nz <= 1.f);
    float pnx = fminf(fmaxf(nx, 0.f), 1.f);
    float pny = fminf(fmaxf(ny, 0.f), 1.f);
    float pnz = fminf(fmaxf(nz, 0.f), 1.f);

    const float2* tab = (const float2*)g_tab;

    // ---- single gather pass over OWN 8 levels; partials -> LDS ----
    float f0o[8], f1o[8];
#pragma unroll
    for (int j = 0; j < 8; ++j) {
        float res = p ? rt.r[8+j] : rt.r[j];          // constant-index select
        const float2* tl = tab + (size_t)(p * 8 + j) * TSZ;
        float fx = pnx * res, fy = pny * res, fz = pnz * res;
        float x0 = floorf(fx), y0 = floorf(fy), z0 = floorf(fz);
        float wx = fx - x0, wy = fy - y0, wz = fz - z0;
        float omx = 1.f - wx, omy = 1.f - wy, omz = 1.f - wz;
        unsigned ux = (unsigned)x0, uy = (unsigned)y0, uz = (unsigned)z0;
        unsigned hx0 = ux,        hx1 = ux + 1u;
        unsigned hy0 = uy * PR1,  hy1 = (uy + 1u) * PR1;
        unsigned hz0 = uz * PR2,  hz1 = (uz + 1u) * PR2;
        float f0 = 0.f, f1 = 0.f;
        float lxa = 0.f, lxb = 0.f, lya = 0.f, lyb = 0.f, lza = 0.f, lzb = 0.f;
#pragma unroll
        for (int c = 0; c < 8; ++c) {
            unsigned hh = ((c & 4) ? hx1 : hx0) ^ ((c & 2) ? hy1 : hy0) ^ ((c & 1) ? hz1 : hz0);
            float2 fv = tl[hh & TMASK];
            float wxv = (c & 4) ? wx : omx;
            float wyv = (c & 2) ? wy : omy;
            float wzv = (c & 1) ? wz : omz;
            // forward: wc = (x*y)*z, each op rounded; f += fv*wc seq c=0..7
            float wgt = wxv * wyv;
            wgt = wgt * wzv;
            float t0 = fv.x * wgt;
            float t1 = fv.y * wgt;
            f0 = f0 + t0;
            f1 = f1 + t1;
            // gradient partials (sign flip by corner bit is exact)
            float pyz = wyv * wzv;
            float pxz = wxv * wzv;
            float pxy = wxv * wyv;
            float spx = (c & 4) ? pyz : -pyz;
            float spy = (c & 2) ? pxz : -pxz;
            float spz = (c & 1) ? pxy : -pxy;
            lxa = lxa + fv.x * spx;  lxb = lxb + fv.y * spx;
            lya = lya + fv.x * spy;  lyb = lyb + fv.y * spy;
            lza = lza + fv.x * spz;  lzb = lzb + fv.y * spz;
        }
        f0o[j] = f0; f1o[j] = f1;
        sm[j*6+0][lt] = lxa;  sm[j*6+1][lt] = lxb;
        sm[j*6+2][lt] = lya;  sm[j*6+3][lt] = lyb;
        sm[j*6+4][lt] = lza;  sm[j*6+5][lt] = lzb;
    }

    // ---- exchange f with partner lane; build z1 in EXACT level order ----
    float z1[32];
#pragma unroll
    for (int i = 0; i < 32; ++i) z1[i] = 0.f;

    float hi0[8], hi1[8];
#pragma unroll
    for (int j = 0; j < 8; ++j) {
        float t0 = __shfl_xor(f0o[j], 1, 64);
        float t1 = __shfl_xor(f1o[j], 1, 64);
        float lo0 = p ? t0 : f0o[j];      // level j feats (bit-exact copy)
        float lo1 = p ? t1 : f1o[j];
        hi0[j] = p ? f0o[j] : t0;         // level 8+j feats
        hi1[j] = p ? f1o[j] : t1;
        const float* w1a = g_W1 + (2*j) * 32;
        const float* w1b = g_W1 + (2*j+1) * 32;
#pragma unroll
        for (int i = 0; i < 32; ++i) {
            float acc = fmaf(lo0, w1a[i], z1[i]);    // k=2j then k=2j+1
            z1[i] = fmaf(lo1, w1b[i], acc);
        }
    }
#pragma unroll
    for (int j = 0; j < 8; ++j) {
        const float* w1a = g_W1 + (2*(8+j)) * 32;
        const float* w1b = g_W1 + (2*(8+j)+1) * 32;
#pragma unroll
        for (int i = 0; i < 32; ++i) {
            float acc = fmaf(hi0[j], w1a[i], z1[i]);
            z1[i] = fmaf(hi1[j], w1b[i], acc);
        }
    }

    // ---- relu + second layer (sgemm FMA chain, ascending j) ----
    unsigned mask = 0u;
    float sh[32];
#pragma unroll
    for (int o = 0; o < 32; ++o) sh[o] = 0.f;
#pragma unroll
    for (int i = 0; i < 32; ++i) {
        bool on = (z1[i] > 0.f);
        if (on) mask |= (1u << i);
        float h = on ? z1[i] : 0.f;
        const float* w2r = g_W2 + i * 32;
#pragma unroll
        for (int o = 0; o < 32; ++o) sh[o] = fmaf(h, w2r[o], sh[o]);
    }

    const float C0c = 0.28209479177387814f;
    float d0 = C0c * sh[0], d1 = C0c * sh[1];

    // ---- view dirs + SH basis + scat ----
    float rx0 = g_rx[0], rx1 = g_rx[1], rx2 = g_rx[2];
    float dxw = rx0 - posx, dyw = rx1 - posy, dzw = rx2 - posz;
    float dnorm = sqrtf(dxw*dxw + dyw*dyw + dzw*dzw);
    float dinv = 1.f / fmaxf(dnorm, 1e-20f);
    float X = dxw * dinv, Yd = dyw * dinv, Z = dzw * dinv;
    float xx = X*X, yy = Yd*Yd, zz = Z*Z;
    float xy = X*Yd, yz = Yd*Z, xz = X*Z;
    float Yb[16];
    Yb[0]  = 0.28209479177387814f;
    Yb[1]  = -0.4886025119029199f * Yd;
    Yb[2]  =  0.4886025119029199f * Z;
    Yb[3]  = -0.4886025119029199f * X;
    Yb[4]  =  1.0925484305920792f * xy;
    Yb[5]  = -1.0925484305920792f * yz;
    Yb[6]  =  0.31539156525252005f * (2.f*zz - xx - yy);
    Yb[7]  = -1.0925484305920792f * xz;
    Yb[8]  =  0.5462742152960396f * (xx - yy);
    Yb[9]  = -0.5900435899266435f * Yd * (3.f*xx - yy);
    Yb[10] =  2.890611442640554f  * xy * Z;
    Yb[11] = -0.4570457994644658f * Yd * (4.f*zz - xx - yy);
    Yb[12] =  0.3731763325901154f * Z * (2.f*zz - 3.f*xx - 3.f*yy);
    Yb[13] = -0.4570457994644658f * X * (4.f*zz - xx - yy);
    Yb[14] =  1.445305721320277f  * Z * (xx - yy);
    Yb[15] = -0.5900435899266435f * X * (xx - 3.f*yy);

    int deg = g_deg[0];
    int nact = (deg + 1) * (deg + 1);
    float sc0 = 0.f, sc1 = 0.f;
#pragma unroll
    for (int c = 0; c < 16; ++c) {
        float yc = (c < nact) ? Yb[c] : 0.f;
        sc0 = fmaf(yc, sh[2*c+0], sc0);
        sc1 = fmaf(yc, sh[2*c+1], sc1);
    }

    // ---- split the 39 stores between the lane pair ----
    float* op = g_out + (size_t)n * 39;
    if (p == 0) {
        op[0] = sel ? d0  : 0.f;
        op[1] = sel ? d1  : 0.f;
        op[2] = sel ? sc0 : 0.f;
        op[3] = sel ? sc1 : 0.f;
#pragma unroll
        for (int c = 0; c < 13; ++c) op[7 + c] = sel ? sh[c] : 0.f;
    } else {
#pragma unroll
        for (int c = 13; c < 32; ++c) op[7 + c] = sel ? sh[c] : 0.f;
    }

    // ---- backward head: q = C0*d/|d| ----
    float ss = d0*d0 + d1*d1;
    float q0 = 0.f, q1 = 0.f;
    if (ss > 0.f) {
        float sr = sqrtf(ss);
        q0 = C0c * d0 / sr;
        q1 = C0c * d1 / sr;
    }
    float dzv[32];
#pragma unroll
    for (int i = 0; i < 32; ++i) {
        float dh = fmaf(q0, g_W2[i*32+0], q1 * g_W2[i*32+1]);
        dzv[i] = ((mask >> i) & 1u) ? dh : 0.f;
    }

    // ---- backward over OWN levels: da/db from W1, partials from LDS ----
    float gx = 0.f, gy = 0.f, gz = 0.f;
    const float4* w1v = (const float4*)g_W1;   // row r = w1v[r*8 .. r*8+7]
    int rbase = p * 16;
#pragma unroll
    for (int j = 0; j < 8; ++j) {
        const float4* wa = w1v + (size_t)(rbase + 2*j) * 8;
        const float4* wb = wa + 8;
        float da = 0.f, db = 0.f;
#pragma unroll
        for (int k = 0; k < 8; ++k) {
            float4 va = wa[k], vb = wb[k];
            da = fmaf(va.x, dzv[4*k+0], da);
            da = fmaf(va.y, dzv[4*k+1], da);
            da = fmaf(va.z, dzv[4*k+2], da);
            da = fmaf(va.w, dzv[4*k+3], da);
            db = fmaf(vb.x, dzv[4*k+0], db);
            db = fmaf(vb.y, dzv[4*k+1], db);
            db = fmaf(vb.z, dzv[4*k+2], db);
            db = fmaf(vb.w, dzv[4*k+3], db);
        }
        float xa = sm[j*6+0][lt], xb = sm[j*6+1][lt];
        float ya = sm[j*6+2][lt], yb = sm[j*6+3][lt];
        float za = sm[j*6+4][lt], zb = sm[j*6+5][lt];
        float res = p ? rt.r[8+j] : rt.r[j];
        gx = fmaf(res, fmaf(da, xa, db * xb), gx);
        gy = fmaf(res, fmaf(da, ya, db * yb), gy);
        gz = fmaf(res, fmaf(da, za, db * zb), gz);
    }
    // combine partner halves (commutative add -> identical in both lanes)
    float tx = __shfl_xor(gx, 1, 64);
    float ty = __shfl_xor(gy, 1, 64);
    float tz = __shfl_xor(gz, 1, 64);
    gx = gx + tx; gy = gy + ty; gz = gz + tz;

    // ---- world-space normal ----
    float gwx = gx / s0, gwy = gy / s1, gwz = gz / s2;
    float gn = sqrtf(gwx*gwx + gwy*gwy + gwz*gwz);
    float ginv = -1.f / fmaxf(gn, 1e-20f);
    if (p == 0) {
        op[4] = sel ? gwx * ginv : 0.f;
        op[5] = sel ? gwy * ginv : 0.f;
        op[6] = sel ? gwz * ginv : 0.f;
    }
}

extern "C" void kernel_launch(void* const* d_in, const int* in_sizes, int n_in,
                              void* d_out, int out_size, void* d_ws, size_t ws_size,
                              hipStream_t stream)
{
    const float* g_pos  = (const float*)d_in[0];
    const float* g_rx   = (const float*)d_in[1];
    const float* g_tab  = (const float*)d_in[2];
    const float* g_W1   = (const float*)d_in[3];
    const float* g_W2   = (const float*)d_in[4];
    const float* g_aabb = (const float*)d_in[5];
    const int*   g_deg  = (const int*)d_in[6];
    float* g_out = (float*)d_out;

    int N = in_sizes[0] / 3;

    // RES exactly as the reference: python float64 exp/log/pow, cast to fp32.
    ResT rt;
    double scale = exp((log(4096.0) - log(16.0)) / 15.0);
    for (int l = 0; l < NLV; ++l) rt.r[l] = (float)(16.0 * pow(scale, (double)l));

    long long threads = 2LL * N;
    int blocks = (int)((threads + 255) / 256);
    ngp_fused<<<blocks, 256, 0, stream>>>(g_pos, g_rx, g_tab, g_W1, g_W2,
                                          g_aabb, g_deg, g_out, N, rt);
}

// Round 8
// 360.918 us; speedup vs baseline: 2.0664x; 1.1259x over previous
//
#include <hip/hip_runtime.h>
#include <cmath>

// Forbid FMA contraction: the reference check is a float32 numpy replay with
// individually-rounded ops. We opt into FMA explicitly (fmaf) only where
// BLAS sgemm itself uses an FMA chain.
#pragma clang fp contract(off)

#define NLV 16
#define TSZ (1u << 19)
#define TMASK (TSZ - 1u)
#define PR1 2654435761u
#define PR2 805459861u

struct ResT { float r[NLV]; };

// ---------- shared helpers (bit-exact fp32, matches np reference) ----------
__device__ __forceinline__ void aabb_norm(
    const float* __restrict__ g_aabb, float posx, float posy, float posz,
    float& s0, float& s1, float& s2,
    float& pnx, float& pny, float& pnz, bool& sel)
{
    float a0 = g_aabb[0], a1 = g_aabb[1], a2 = g_aabb[2];
    s0 = fmaxf(g_aabb[3] - a0, 1e-6f);
    s1 = fmaxf(g_aabb[4] - a1, 1e-6f);
    s2 = fmaxf(g_aabb[5] - a2, 1e-6f);
    float nx = (posx - a0) / s0;
    float ny = (posy - a1) / s1;
    float nz = (posz - a2) / s2;
    sel = (nx >= 0.f) && (nx <= 1.f) && (ny >= 0.f) && (ny <= 1.f)
       && (nz >= 0.f) && (nz <= 1.f);
    pnx = fminf(fmaxf(nx, 0.f), 1.f);
    pny = fminf(fmaxf(ny, 0.f), 1.f);
    pnz = fminf(fmaxf(nz, 0.f), 1.f);
}

// =====================================================================
// PASS A: one (point, level) per thread. Block b -> level (b&15),
// chunk (b>>4). Round-robin XCD = b%8 => level l only ever runs on
// XCD l%8, so each level's 4 MB table slice stays resident in ONE L2.
// Writes f0,f1 + 6 gradient partials to coalesced workspace planes.
// =====================================================================
__global__ __launch_bounds__(256) void level_gather(
    const float* __restrict__ g_pos,
    const float* __restrict__ g_tab,
    const float* __restrict__ g_aabb,
    float* __restrict__ ws,
    int N, ResT rt)
{
    int b = blockIdx.x;
    int lvl = b & 15;
    int n = (b >> 4) * 256 + threadIdx.x;
    if (n >= N) return;

    float posx = g_pos[3*n+0], posy = g_pos[3*n+1], posz = g_pos[3*n+2];
    float s0, s1, s2, pnx, pny, pnz; bool sel;
    aabb_norm(g_aabb, posx, posy, posz, s0, s1, s2, pnx, pny, pnz, sel);

    float res = rt.r[lvl];                       // wave-uniform scalar
    const float2* tl = (const float2*)g_tab + (size_t)lvl * TSZ;

    float fx = pnx * res, fy = pny * res, fz = pnz * res;
    float x0 = floorf(fx), y0 = floorf(fy), z0 = floorf(fz);
    float wx = fx - x0, wy = fy - y0, wz = fz - z0;
    float omx = 1.f - wx, omy = 1.f - wy, omz = 1.f - wz;
    unsigned ux = (unsigned)x0, uy = (unsigned)y0, uz = (unsigned)z0;
    unsigned hx0 = ux,        hx1 = ux + 1u;
    unsigned hy0 = uy * PR1,  hy1 = (uy + 1u) * PR1;
    unsigned hz0 = uz * PR2,  hz1 = (uz + 1u) * PR2;
    float f0 = 0.f, f1 = 0.f;
    float lxa = 0.f, lxb = 0.f, lya = 0.f, lyb = 0.f, lza = 0.f, lzb = 0.f;
#pragma unroll
    for (int c = 0; c < 8; ++c) {
        unsigned hh = ((c & 4) ? hx1 : hx0) ^ ((c & 2) ? hy1 : hy0) ^ ((c & 1) ? hz1 : hz0);
        float2 fv = tl[hh & TMASK];
        float wxv = (c & 4) ? wx : omx;
        float wyv = (c & 2) ? wy : omy;
        float wzv = (c & 1) ? wz : omz;
        // forward: wc = (x*y)*z, each op rounded; f += fv*wc seq c=0..7
        float wgt = wxv * wyv;
        wgt = wgt * wzv;
        float t0 = fv.x * wgt;
        float t1 = fv.y * wgt;
        f0 = f0 + t0;
        f1 = f1 + t1;
        // gradient partials (sign flip by corner bit is exact)
        float pyz = wyv * wzv;
        float pxz = wxv * wzv;
        float pxy = wxv * wyv;
        float spx = (c & 4) ? pyz : -pyz;
        float spy = (c & 2) ? pxz : -pxz;
        float spz = (c & 1) ? pxy : -pxy;
        lxa = lxa + fv.x * spx;  lxb = lxb + fv.y * spx;
        lya = lya + fv.x * spy;  lyb = lyb + fv.y * spy;
        lza = lza + fv.x * spz;  lzb = lzb + fv.y * spz;
    }

    size_t LN = (size_t)NLV * N;
    size_t base = (size_t)lvl * N + n;
    ws[0*LN + base] = f0;
    ws[1*LN + base] = f1;
    ws[2*LN + base] = lxa;
    ws[3*LN + base] = lxb;
    ws[4*LN + base] = lya;
    ws[5*LN + base] = lyb;
    ws[6*LN + base] = lza;
    ws[7*LN + base] = lzb;
}

// =====================================================================
// PASS B: one thread per point. No table access; streams f/partials
// from workspace, replays the exact reference z1/sh chain, backward.
// =====================================================================
__global__ __launch_bounds__(256) void mlp_bwd(
    const float* __restrict__ g_pos,
    const float* __restrict__ g_rx,
    const float* __restrict__ g_W1,
    const float* __restrict__ g_W2,
    const float* __restrict__ g_aabb,
    const int*   __restrict__ g_deg,
    const float* __restrict__ ws,
    float* __restrict__ g_out,
    int N, ResT rt)
{
    int n = blockIdx.x * 256 + threadIdx.x;
    if (n >= N) return;

    float posx = g_pos[3*n+0], posy = g_pos[3*n+1], posz = g_pos[3*n+2];
    float s0, s1, s2, pnx, pny, pnz; bool sel;
    aabb_norm(g_aabb, posx, posy, posz, s0, s1, s2, pnx, pny, pnz, sel);
    (void)pnx; (void)pny; (void)pnz;

    size_t LN = (size_t)NLV * N;
    const float* f0w = ws + 0*LN;
    const float* f1w = ws + 1*LN;

    // ---- z1 = feats@W1, exact level order, sgemm FMA chain ascending k ----
    float z1[32];
#pragma unroll
    for (int i = 0; i < 32; ++i) z1[i] = 0.f;
    for (int l = 0; l < NLV; ++l) {
        float f0 = f0w[(size_t)l * N + n];
        float f1 = f1w[(size_t)l * N + n];
        const float* w1a = g_W1 + (2*l) * 32;
        const float* w1b = g_W1 + (2*l+1) * 32;
#pragma unroll
        for (int i = 0; i < 32; ++i) {
            float acc = fmaf(f0, w1a[i], z1[i]);   // k=2l then k=2l+1
            z1[i] = fmaf(f1, w1b[i], acc);
        }
    }

    // ---- relu + second layer (sgemm FMA chain, ascending j) ----
    unsigned mask = 0u;
    float sh[32];
#pragma unroll
    for (int o = 0; o < 32; ++o) sh[o] = 0.f;
#pragma unroll
    for (int i = 0; i < 32; ++i) {
        bool on = (z1[i] > 0.f);
        if (on) mask |= (1u << i);
        float h = on ? z1[i] : 0.f;
        const float* w2r = g_W2 + i * 32;
#pragma unroll
        for (int o = 0; o < 32; ++o) sh[o] = fmaf(h, w2r[o], sh[o]);
    }

    const float C0c = 0.28209479177387814f;
    float d0 = C0c * sh[0], d1 = C0c * sh[1];

    // ---- view dirs + SH basis + scat ----
    float rx0 = g_rx[0], rx1 = g_rx[1], rx2 = g_rx[2];
    float dxw = rx0 - posx, dyw = rx1 - posy, dzw = rx2 - posz;
    float dnorm = sqrtf(dxw*dxw + dyw*dyw + dzw*dzw);
    float dinv = 1.f / fmaxf(dnorm, 1e-20f);
    float X = dxw * dinv, Yd = dyw * dinv, Z = dzw * dinv;
    float xx = X*X, yy = Yd*Yd, zz = Z*Z;
    float xy = X*Yd, yz = Yd*Z, xz = X*Z;
    float Yb[16];
    Yb[0]  = 0.28209479177387814f;
    Yb[1]  = -0.4886025119029199f * Yd;
    Yb[2]  =  0.4886025119029199f * Z;
    Yb[3]  = -0.4886025119029199f * X;
    Yb[4]  =  1.0925484305920792f * xy;
    Yb[5]  = -1.0925484305920792f * yz;
    Yb[6]  =  0.31539156525252005f * (2.f*zz - xx - yy);
    Yb[7]  = -1.0925484305920792f * xz;
    Yb[8]  =  0.5462742152960396f * (xx - yy);
    Yb[9]  = -0.5900435899266435f * Yd * (3.f*xx - yy);
    Yb[10] =  2.890611442640554f  * xy * Z;
    Yb[11] = -0.4570457994644658f * Yd * (4.f*zz - xx - yy);
    Yb[12] =  0.3731763325901154f * Z * (2.f*zz - 3.f*xx - 3.f*yy);
    Yb[13] = -0.4570457994644658f * X * (4.f*zz - xx - yy);
    Yb[14] =  1.445305721320277f  * Z * (xx - yy);
    Yb[15] = -0.5900435899266435f * X * (xx - 3.f*yy);

    int deg = g_deg[0];
    int nact = (deg + 1) * (deg + 1);
    float sc0 = 0.f, sc1 = 0.f;
#pragma unroll
    for (int c = 0; c < 16; ++c) {
        float yc = (c < nact) ? Yb[c] : 0.f;
        sc0 = fmaf(yc, sh[2*c+0], sc0);
        sc1 = fmaf(yc, sh[2*c+1], sc1);
    }

    float* op = g_out + (size_t)n * 39;
    op[0] = sel ? d0  : 0.f;
    op[1] = sel ? d1  : 0.f;
    op[2] = sel ? sc0 : 0.f;
    op[3] = sel ? sc1 : 0.f;
#pragma unroll
    for (int c = 0; c < 32; ++c) op[7 + c] = sel ? sh[c] : 0.f;

    // ---- backward head: q = C0*d/|d| ----
    float ss = d0*d0 + d1*d1;
    float q0 = 0.f, q1 = 0.f;
    if (ss > 0.f) {
        float sr = sqrtf(ss);
        q0 = C0c * d0 / sr;
        q1 = C0c * d1 / sr;
    }
    float dzv[32];
#pragma unroll
    for (int i = 0; i < 32; ++i) {
        float dh = fmaf(q0, g_W2[i*32+0], q1 * g_W2[i*32+1]);
        dzv[i] = ((mask >> i) & 1u) ? dh : 0.f;
    }

    // ---- gradient: per level, da/db from W1 (L1-hit) x partials from ws ----
    const float* mxaw = ws + 2*LN;
    const float* mxbw = ws + 3*LN;
    const float* myaw = ws + 4*LN;
    const float* mybw = ws + 5*LN;
    const float* mzaw = ws + 6*LN;
    const float* mzbw = ws + 7*LN;
    float gx = 0.f, gy = 0.f, gz = 0.f;
    const float4* w1v = (const float4*)g_W1;   // row r = w1v[r*8 .. r*8+7]
    for (int l = 0; l < NLV; ++l) {
        const float4* wa = w1v + (size_t)(2*l) * 8;
        const float4* wb = wa + 8;
        float da = 0.f, db = 0.f;
#pragma unroll
        for (int k = 0; k < 8; ++k) {
            float4 va = wa[k], vb = wb[k];
            da = fmaf(va.x, dzv[4*k+0], da);
            da = fmaf(va.y, dzv[4*k+1], da);
            da = fmaf(va.z, dzv[4*k+2], da);
            da = fmaf(va.w, dzv[4*k+3], da);
            db = fmaf(vb.x, dzv[4*k+0], db);
            db = fmaf(vb.y, dzv[4*k+1], db);
            db = fmaf(vb.z, dzv[4*k+2], db);
            db = fmaf(vb.w, dzv[4*k+3], db);
        }
        size_t base = (size_t)l * N + n;
        float xa = mxaw[base], xb = mxbw[base];
        float ya = myaw[base], yb = mybw[base];
        float za = mzaw[base], zb = mzbw[base];
        float res = rt.r[l];
        gx = fmaf(res, fmaf(da, xa, db * xb), gx);
        gy = fmaf(res, fmaf(da, ya, db * yb), gy);
        gz = fmaf(res, fmaf(da, za, db * zb), gz);
    }

    // ---- world-space normal ----
    float gwx = gx / s0, gwy = gy / s1, gwz = gz / s2;
    float gn = sqrtf(gwx*gwx + gwy*gwy + gwz*gwz);
    float ginv = -1.f / fmaxf(gn, 1e-20f);
    op[4] = sel ? gwx * ginv : 0.f;
    op[5] = sel ? gwy * ginv : 0.f;
    op[6] = sel ? gwz * ginv : 0.f;
}

// =====================================================================
// FALLBACK (round-7 fused kernel) if ws_size is too small.
// =====================================================================
__global__ __launch_bounds__(256, 2) void ngp_fused(
    const float* __restrict__ g_pos,
    const float* __restrict__ g_rx,
    const float* __restrict__ g_tab,
    const float* __restrict__ g_W1,
    const float* __restrict__ g_W2,
    const float* __restrict__ g_aabb,
    const int*   __restrict__ g_deg,
    float* __restrict__ g_out,
    int N, ResT rt)
{
    __shared__ float sm[48][256];

    int tid = blockIdx.x * 256 + threadIdx.x;
    int lt  = threadIdx.x;
    int n = tid >> 1;
    int p = tid & 1;
    if (n >= N) return;

    float posx = g_pos[3*n+0], posy = g_pos[3*n+1], posz = g_pos[3*n+2];
    float s0, s1, s2, pnx, pny, pnz; bool sel;
    aabb_norm(g_aabb, posx, posy, posz, s0, s1, s2, pnx, pny, pnz, sel);

    const float2* tab = (const float2*)g_tab;
    float f0o[8], f1o[8];
#pragma unroll
    for (int j = 0; j < 8; ++j) {
        float res = p ? rt.r[8+j] : rt.r[j];
        const float2* tl = tab + (size_t)(p * 8 + j) * TSZ;
        float fx = pnx * res, fy = pny * res, fz = pnz * res;
        float x0 = floorf(fx), y0 = floorf(fy), z0 = floorf(fz);
        float wx = fx - x0, wy = fy - y0, wz = fz - z0;
        float omx = 1.f - wx, omy = 1.f - wy, omz = 1.f - wz;
        unsigned ux = (unsigned)x0, uy = (unsigned)y0, uz = (unsigned)z0;
        unsigned hx0 = ux,        hx1 = ux + 1u;
        unsigned hy0 = uy * PR1,  hy1 = (uy + 1u) * PR1;
        unsigned hz0 = uz * PR2,  hz1 = (uz + 1u) * PR2;
        float f0 = 0.f, f1 = 0.f;
        float lxa = 0.f, lxb = 0.f, lya = 0.f, lyb = 0.f, lza = 0.f, lzb = 0.f;
#pragma unroll
        for (int c = 0; c < 8; ++c) {
            unsigned hh = ((c & 4) ? hx1 : hx0) ^ ((c & 2) ? hy1 : hy0) ^ ((c & 1) ? hz1 : hz0);
            float2 fv = tl[hh & TMASK];
            float wxv = (c & 4) ? wx : omx;
            float wyv = (c & 2) ? wy : omy;
            float wzv = (c & 1) ? wz : omz;
            float wgt = wxv * wyv;
            wgt = wgt * wzv;
            float t0 = fv.x * wgt;
            float t1 = fv.y * wgt;
            f0 = f0 + t0;
            f1 = f1 + t1;
            float pyz = wyv * wzv;
            float pxz = wxv * wzv;
            float pxy = wxv * wyv;
            float spx = (c & 4) ? pyz : -pyz;
            float spy = (c & 2) ? pxz : -pxz;
            float spz = (c & 1) ? pxy : -pxy;
            lxa = lxa + fv.x * spx;  lxb = lxb + fv.y * spx;
            lya = lya + fv.x * spy;  lyb = lyb + fv.y * spy;
            lza = lza + fv.x * spz;  lzb = lzb + fv.y * spz;
        }
        f0o[j] = f0; f1o[j] = f1;
        sm[j*6+0][lt] = lxa;  sm[j*6+1][lt] = lxb;
        sm[j*6+2][lt] = lya;  sm[j*6+3][lt] = lyb;
        sm[j*6+4][lt] = lza;  sm[j*6+5][lt] = lzb;
    }

    float z1[32];
#pragma unroll
    for (int i = 0; i < 32; ++i) z1[i] = 0.f;
    float hi0[8], hi1[8];
#pragma unroll
    for (int j = 0; j < 8; ++j) {
        float t0 = __shfl_xor(f0o[j], 1, 64);
        float t1 = __shfl_xor(f1o[j], 1, 64);
        float lo0 = p ? t0 : f0o[j];
        float lo1 = p ? t1 : f1o[j];
        hi0[j] = p ? f0o[j] : t0;
        hi1[j] = p ? f1o[j] : t1;
        const float* w1a = g_W1 + (2*j) * 32;
        const float* w1b = g_W1 + (2*j+1) * 32;
#pragma unroll
        for (int i = 0; i < 32; ++i) {
            float acc = fmaf(lo0, w1a[i], z1[i]);
            z1[i] = fmaf(lo1, w1b[i], acc);
        }
    }
#pragma unroll
    for (int j = 0; j < 8; ++j) {
        const float* w1a = g_W1 + (2*(8+j)) * 32;
        const float* w1b = g_W1 + (2*(8+j)+1) * 32;
#pragma unroll
        for (int i = 0; i < 32; ++i) {
            float acc = fmaf(hi0[j], w1a[i], z1[i]);
            z1[i] = fmaf(hi1[j], w1b[i], acc);
        }
    }

    unsigned mask = 0u;
    float sh[32];
#pragma unroll
    for (int o = 0; o < 32; ++o) sh[o] = 0.f;
#pragma unroll
    for (int i = 0; i < 32; ++i) {
        bool on = (z1[i] > 0.f);
        if (on) mask |= (1u << i);
        float h = on ? z1[i] : 0.f;
        const float* w2r = g_W2 + i * 32;
#pragma unroll
        for (int o = 0; o < 32; ++o) sh[o] = fmaf(h, w2r[o], sh[o]);
    }

    const float C0c = 0.28209479177387814f;
    float d0 = C0c * sh[0], d1 = C0c * sh[1];

    float rx0 = g_rx[0], rx1 = g_rx[1], rx2 = g_rx[2];
    float dxw = rx0 - posx, dyw = rx1 - posy, dzw = rx2 - posz;
    float dnorm = sqrtf(dxw*dxw + dyw*dyw + dzw*dzw);
    float dinv = 1.f / fmaxf(dnorm, 1e-20f);
    float X = dxw * dinv, Yd = dyw * dinv, Z = dzw * dinv;
    float xx = X*X, yy = Yd*Yd, zz = Z*Z;
    float xy = X*Yd, yz = Yd*Z, xz = X*Z;
    float Yb[16];
    Yb[0]  = 0.28209479177387814f;
    Yb[1]  = -0.4886025119029199f * Yd;
    Yb[2]  =  0.4886025119029199f * Z;
    Yb[3]  = -0.4886025119029199f * X;
    Yb[4]  =  1.0925484305920792f * xy;
    Yb[5]  = -1.0925484305920792f * yz;
    Yb[6]  =  0.31539156525252005f * (2.f*zz - xx - yy);
    Yb[7]  = -1.0925484305920792f * xz;
    Yb[8]  =  0.5462742152960396f * (xx - yy);
    Yb[9]  = -0.5900435899266435f * Yd * (3.f*xx - yy);
    Yb[10] =  2.890611442640554f  * xy * Z;
    Yb[11] = -0.4570457994644658f * Yd * (4.f*zz - xx - yy);
    Yb[12] =  0.3731763325901154f * Z * (2.f*zz - 3.f*xx - 3.f*yy);
    Yb[13] = -0.4570457994644658f * X * (4.f*zz - xx - yy);
    Yb[14] =  1.445305721320277f  * Z * (xx - yy);
    Yb[15] = -0.5900435899266435f * X * (xx - 3.f*yy);

    int deg = g_deg[0];
    int nact = (deg + 1) * (deg + 1);
    float sc0 = 0.f, sc1 = 0.f;
#pragma unroll
    for (int c = 0; c < 16; ++c) {
        float yc = (c < nact) ? Yb[c] : 0.f;
        sc0 = fmaf(yc, sh[2*c+0], sc0);
        sc1 = fmaf(yc, sh[2*c+1], sc1);
    }

    float* op = g_out + (size_t)n * 39;
    if (p == 0) {
        op[0] = sel ? d0  : 0.f;
        op[1] = sel ? d1  : 0.f;
        op[2] = sel ? sc0 : 0.f;
        op[3] = sel ? sc1 : 0.f;
#pragma unroll
        for (int c = 0; c < 13; ++c) op[7 + c] = sel ? sh[c] : 0.f;
    } else {
#pragma unroll
        for (int c = 13; c < 32; ++c) op[7 + c] = sel ? sh[c] : 0.f;
    }

    float ss = d0*d0 + d1*d1;
    float q0 = 0.f, q1 = 0.f;
    if (ss > 0.f) {
        float sr = sqrtf(ss);
        q0 = C0c * d0 / sr;
        q1 = C0c * d1 / sr;
    }
    float dzv[32];
#pragma unroll
    for (int i = 0; i < 32; ++i) {
        float dh = fmaf(q0, g_W2[i*32+0], q1 * g_W2[i*32+1]);
        dzv[i] = ((mask >> i) & 1u) ? dh : 0.f;
    }

    float gx = 0.f, gy = 0.f, gz = 0.f;
    const float4* w1v = (const float4*)g_W1;
    int rbase = p * 16;
#pragma unroll
    for (int j = 0; j < 8; ++j) {
        const float4* wa = w1v + (size_t)(rbase + 2*j) * 8;
        const float4* wb = wa + 8;
        float da = 0.f, db = 0.f;
#pragma unroll
        for (int k = 0; k < 8; ++k) {
            float4 va = wa[k], vb = wb[k];
            da = fmaf(va.x, dzv[4*k+0], da);
            da = fmaf(va.y, dzv[4*k+1], da);
            da = fmaf(va.z, dzv[4*k+2], da);
            da = fmaf(va.w, dzv[4*k+3], da);
            db = fmaf(vb.x, dzv[4*k+0], db);
            db = fmaf(vb.y, dzv[4*k+1], db);
            db = fmaf(vb.z, dzv[4*k+2], db);
            db = fmaf(vb.w, dzv[4*k+3], db);
        }
        float xa = sm[j*6+0][lt], xb = sm[j*6+1][lt];
        float ya = sm[j*6+2][lt], yb = sm[j*6+3][lt];
        float za = sm[j*6+4][lt], zb = sm[j*6+5][lt];
        float res = p ? rt.r[8+j] : rt.r[j];
        gx = fmaf(res, fmaf(da, xa, db * xb), gx);
        gy = fmaf(res, fmaf(da, ya, db * yb), gy);
        gz = fmaf(res, fmaf(da, za, db * zb), gz);
    }
    float tx = __shfl_xor(gx, 1, 64);
    float ty = __shfl_xor(gy, 1, 64);
    float tz = __shfl_xor(gz, 1, 64);
    gx = gx + tx; gy = gy + ty; gz = gz + tz;

    float gwx = gx / s0, gwy = gy / s1, gwz = gz / s2;
    float gn = sqrtf(gwx*gwx + gwy*gwy + gwz*gwz);
    float ginv = -1.f / fmaxf(gn, 1e-20f);
    if (p == 0) {
        op[4] = sel ? gwx * ginv : 0.f;
        op[5] = sel ? gwy * ginv : 0.f;
        op[6] = sel ? gwz * ginv : 0.f;
    }
}

extern "C" void kernel_launch(void* const* d_in, const int* in_sizes, int n_in,
                              void* d_out, int out_size, void* d_ws, size_t ws_size,
                              hipStream_t stream)
{
    const float* g_pos  = (const float*)d_in[0];
    const float* g_rx   = (const float*)d_in[1];
    const float* g_tab  = (const float*)d_in[2];
    const float* g_W1   = (const float*)d_in[3];
    const float* g_W2   = (const float*)d_in[4];
    const float* g_aabb = (const float*)d_in[5];
    const int*   g_deg  = (const int*)d_in[6];
    float* g_out = (float*)d_out;

    int N = in_sizes[0] / 3;

    // RES exactly as the reference: python float64 exp/log/pow, cast to fp32.
    ResT rt;
    double scale = exp((log(4096.0) - log(16.0)) / 15.0);
    for (int l = 0; l < NLV; ++l) rt.r[l] = (float)(16.0 * pow(scale, (double)l));

    size_t need = (size_t)NLV * N * 8 * sizeof(float);   // 134 MB at N=262144
    if (ws_size >= need) {
        float* ws = (float*)d_ws;
        int chunks = (N + 255) / 256;
        level_gather<<<NLV * chunks, 256, 0, stream>>>(g_pos, g_tab, g_aabb,
                                                       ws, N, rt);
        mlp_bwd<<<chunks, 256, 0, stream>>>(g_pos, g_rx, g_W1, g_W2, g_aabb,
                                            g_deg, ws, g_out, N, rt);
    } else {
        long long threads = 2LL * N;
        int blocks = (int)((threads + 255) / 256);
        ngp_fused<<<blocks, 256, 0, stream>>>(g_pos, g_rx, g_tab, g_W1, g_W2,
                                              g_aabb, g_deg, g_out, N, rt);
    }
}